// Round 11
// baseline (114.065 us; speedup 1.0000x reference)
//
#include <hip/hip_runtime.h>
#include <math.h>

// ---------------------------------------------------------------------------
// Encoder_Flows on MI355X — 8 dispatches. R10 (112.7us) + dbuf DOUT=128 mains.
//   prep  : blocks 0-31 proj1 (dbuf staged GEMM -> YT1 bf16), blocks 32-351
//           weight fp32->bf16 cvt, + tuple scalar.
//   proj_L: 32 blocks, dbuf-pipelined staged GEMM -> YT_L bf16.
//   main_L: 1024x32-row blocks; DOUT=128 mains (L1,L3) now use the same dbuf
//           one-barrier-per-step pipeline (LDS 40.2KB, still 4 blocks/CU);
//           DOUT=256 mains (L2,L4) keep the 2-barrier loop (dbuf would be
//           72KB -> 2 blocks/CU, occupancy loss > pipeline gain).
//           Head blocks (i0<1024): scan-GEMM agg from bf16 YT; then
//           bias+agg+row-L2-norm -> bf16 x (L4: relu -> fp32 out).
// Laws from R6-R9: head-extra work must be coalesced+small; no direct-frag
// global loads; no in-block layer chaining; occupancy before pipelining.
// ---------------------------------------------------------------------------

typedef __attribute__((ext_vector_type(8))) short short8;
typedef __attribute__((ext_vector_type(4))) float f32x4;

constexpr int NROWS = 32768;
constexpr int KROWS = 1024;

static __device__ __forceinline__ unsigned short f2bf(float f) {
    unsigned int u = __float_as_uint(f);
    return (unsigned short)((u + 0x7fffu + ((u >> 16) & 1u)) >> 16);
}

// ---- register staging helpers (tile ROWS x 64, XOR-swizzled LDS) ----------
template<int ROWS>
struct RegsBF {
    short8 v[ROWS / 32];
    __device__ __forceinline__ void load(const unsigned short* src, int ld,
                                         int r0, int k0, int t) {
#pragma unroll
        for (int j = 0; j < ROWS / 32; ++j) {
            int idx = j * 256 + t; int r = idx >> 3, f = idx & 7;
            v[j] = *reinterpret_cast<const short8*>(
                src + (size_t)(r0 + r) * ld + k0 + f * 8);
        }
    }
    __device__ __forceinline__ void store(unsigned short* buf, int t) {
#pragma unroll
        for (int j = 0; j < ROWS / 32; ++j) {
            int idx = j * 256 + t; int r = idx >> 3, f = idx & 7;
            int off = (r * 128 + f * 16) ^ ((r & 7) << 4);
            *reinterpret_cast<short8*>((char*)buf + off) = v[j];
        }
    }
};

template<int ROWS>
struct RegsF32 {
    float4 v[ROWS / 16];
    __device__ __forceinline__ void load(const float* src, int ld,
                                         int r0, int k0, int t) {
#pragma unroll
        for (int j = 0; j < ROWS / 32; ++j) {
            int idx = j * 256 + t; int r = idx >> 3, f = idx & 7;
            const float* p = src + (size_t)(r0 + r) * ld + k0 + f * 8;
            v[2 * j]     = *reinterpret_cast<const float4*>(p);
            v[2 * j + 1] = *reinterpret_cast<const float4*>(p + 4);
        }
    }
    __device__ __forceinline__ void store(unsigned short* buf, int t) {
#pragma unroll
        for (int j = 0; j < ROWS / 32; ++j) {
            int idx = j * 256 + t; int r = idx >> 3, f = idx & 7;
            float4 a = v[2 * j], b = v[2 * j + 1];
            short8 s;
            s[0] = (short)f2bf(a.x); s[1] = (short)f2bf(a.y);
            s[2] = (short)f2bf(a.z); s[3] = (short)f2bf(a.w);
            s[4] = (short)f2bf(b.x); s[5] = (short)f2bf(b.y);
            s[6] = (short)f2bf(b.z); s[7] = (short)f2bf(b.w);
            int off = (r * 128 + f * 16) ^ ((r & 7) << 4);
            *reinterpret_cast<short8*>((char*)buf + off) = s;
        }
    }
};

// ---- MFMA fragment helpers (swizzled LDS read + MFMA over one 64-k tile) ---
template<int BM, int WM, int WN, int FM>
__device__ __forceinline__ void mfma_tile(const unsigned short* Abuf,
    const unsigned short* Bbuf, f32x4 (&acc)[FM][4], int wr_, int wc, int lane)
{
#pragma unroll
    for (int kk = 0; kk < 2; ++kk) {
        short8 a[FM], b[4];
#pragma unroll
        for (int fi = 0; fi < FM; ++fi) {
            const int rA = wr_ * (BM / WM) + fi * 16 + (lane & 15);
            const int off = (rA * 128 + kk * 64 + (lane >> 4) * 16) ^ ((rA & 7) << 4);
            a[fi] = *reinterpret_cast<const short8*>((const char*)Abuf + off);
        }
#pragma unroll
        for (int fj = 0; fj < 4; ++fj) {
            const int rB = wc * 64 + fj * 16 + (lane & 15);
            const int off = (rB * 128 + kk * 64 + (lane >> 4) * 16) ^ ((rB & 7) << 4);
            b[fj] = *reinterpret_cast<const short8*>((const char*)Bbuf + off);
        }
#pragma unroll
        for (int fi = 0; fi < FM; ++fi)
#pragma unroll
            for (int fj = 0; fj < 4; ++fj)
                acc[fi][fj] = __builtin_amdgcn_mfma_f32_16x16x32_bf16(
                    a[fi], b[fj], acc[fi][fj], 0, 0, 0);
    }
}

// ---------------------------------------------------------------------------
// Proj body: Y^T = (X[i0..i0+32) @ W^T)^T, dbuf-pipelined.
// ---------------------------------------------------------------------------
template<int DIN, int DOUT, bool AFP32, bool BFP32>
__device__ __forceinline__ void proj_dbuf(const void* __restrict__ Xv,
    const void* __restrict__ Wv, unsigned short* __restrict__ YT, int i0, int t,
    unsigned short* Ab0, unsigned short* Ab1,
    unsigned short* Bb0, unsigned short* Bb1)
{
    constexpr int WN = DOUT / 64, WM = 4 / WN, FM = DOUT / 128, NT = DIN / 64;
    const int wv = t >> 6, lane = t & 63, wr_ = wv / WN, wc = wv % WN;
    f32x4 acc[FM][4];
#pragma unroll
    for (int fi = 0; fi < FM; ++fi)
#pragma unroll
        for (int fj = 0; fj < 4; ++fj) acc[fi][fj] = (f32x4){0.f, 0.f, 0.f, 0.f};

    RegsF32<32>  arf; RegsBF<32>  arb;
    RegsF32<DOUT> brf; RegsBF<DOUT> brb;
    if (AFP32) arf.load((const float*)Xv, DIN, i0, 0, t);
    else       arb.load((const unsigned short*)Xv, DIN, i0, 0, t);
    if (BFP32) brf.load((const float*)Wv, DIN, 0, 0, t);
    else       brb.load((const unsigned short*)Wv, DIN, 0, 0, t);
    if (AFP32) arf.store(Ab0, t); else arb.store(Ab0, t);
    if (BFP32) brf.store(Bb0, t); else brb.store(Bb0, t);
    if (NT > 1) {
        if (AFP32) arf.load((const float*)Xv, DIN, i0, 64, t);
        else       arb.load((const unsigned short*)Xv, DIN, i0, 64, t);
        if (BFP32) brf.load((const float*)Wv, DIN, 0, 64, t);
        else       brb.load((const unsigned short*)Wv, DIN, 0, 64, t);
    }
    __syncthreads();

    for (int kt = 0; kt < NT; ++kt) {
        const unsigned short* Ac = (kt & 1) ? Ab1 : Ab0;
        const unsigned short* Bc = (kt & 1) ? Bb1 : Bb0;
        mfma_tile<32, WM, WN, FM>(Ac, Bc, acc, wr_, wc, lane);
        if (kt + 1 < NT) {
            unsigned short* An = (kt & 1) ? Ab0 : Ab1;
            unsigned short* Bn = (kt & 1) ? Bb0 : Bb1;
            if (AFP32) arf.store(An, t); else arb.store(An, t);
            if (BFP32) brf.store(Bn, t); else brb.store(Bn, t);
            if (kt + 2 < NT) {
                const int kn = (kt + 2) * 64;
                if (AFP32) arf.load((const float*)Xv, DIN, i0, kn, t);
                else       arb.load((const unsigned short*)Xv, DIN, i0, kn, t);
                if (BFP32) brf.load((const float*)Wv, DIN, 0, kn, t);
                else       brb.load((const unsigned short*)Wv, DIN, 0, kn, t);
            }
        }
        __syncthreads();
    }
#pragma unroll
    for (int fi = 0; fi < FM; ++fi)
#pragma unroll
        for (int fj = 0; fj < 4; ++fj) {
            const int rl0 = wr_ * (32 / WM) + fi * 16 + ((lane >> 4) << 2);
            const int cl  = wc * 64 + fj * 16 + (lane & 15);
            ushort4 y;
            y.x = f2bf(acc[fi][fj][0]); y.y = f2bf(acc[fi][fj][1]);
            y.z = f2bf(acc[fi][fj][2]); y.w = f2bf(acc[fi][fj][3]);
            *reinterpret_cast<ushort4*>(YT + (size_t)cl * KROWS + i0 + rl0) = y;
        }
}

// ---------------------------------------------------------------------------
// prep: blocks [0,32) proj1 -> YT1; blocks [32,352) weight cvt; scalar.
// ---------------------------------------------------------------------------
__global__ __launch_bounds__(256, 2)
void prep_kernel(const float* __restrict__ flow, const float* __restrict__ wl1,
                 const float* __restrict__ wr1, const float* __restrict__ wl2,
                 const float* __restrict__ wr2, const float* __restrict__ wl3,
                 const float* __restrict__ wr3, const float* __restrict__ wl4,
                 const float* __restrict__ wr4,
                 unsigned short* __restrict__ wbf,
                 unsigned short* __restrict__ YT1, float* __restrict__ outscalar)
{
    __shared__ unsigned short Ab0[32 * 64], Ab1[32 * 64];
    __shared__ unsigned short Bb0[128 * 64], Bb1[128 * 64];
    const int t = threadIdx.x, bid = blockIdx.x;
    if (bid >= 32) {
        if (bid == 32 && t == 0) outscalar[0] = 1.0f;
        int g = (bid - 32) * 1024 + t * 4;
        const float* src; int off;
        if      (g < 131072) { src = wr1; off = g; }
        else if (g < 163840) { src = wl2; off = g - 131072; }
        else if (g < 196608) { src = wr2; off = g - 163840; }
        else if (g < 229376) { src = wl3; off = g - 196608; }
        else if (g < 262144) { src = wr3; off = g - 229376; }
        else if (g < 294912) { src = wl4; off = g - 262144; }
        else                 { src = wr4; off = g - 294912; }
        float4 v = *reinterpret_cast<const float4*>(src + off);
        ushort4 o4;
        o4.x = f2bf(v.x); o4.y = f2bf(v.y); o4.z = f2bf(v.z); o4.w = f2bf(v.w);
        *reinterpret_cast<ushort4*>(wbf + g) = o4;
        return;
    }
    proj_dbuf<1024, 128, true, true>(flow, wl1, YT1, bid * 32, t,
                                     Ab0, Ab1, Bb0, Bb1);
}

// ---- proj_L (L2-4): 32 blocks, x bf16 in, bf16 weights --------------------
template<int DIN, int DOUT>
__global__ __launch_bounds__(256, 2)
void proj_kernel(const unsigned short* __restrict__ X,
                 const unsigned short* __restrict__ W,
                 unsigned short* __restrict__ YT)
{
    __shared__ unsigned short Ab0[32 * 64], Ab1[32 * 64];
    __shared__ unsigned short Bb0[DOUT * 64], Bb1[DOUT * 64];
    proj_dbuf<DIN, DOUT, false, false>(X, W, YT, blockIdx.x * 32, threadIdx.x,
                                       Ab0, Ab1, Bb0, Bb1);
}

// ---------------------------------------------------------------------------
// main_L.  MODE 1: bf16 out.  MODE 2: relu -> fp32 out.
// DBUF=1 (DOUT=128): one-barrier-per-step double-buffered k-loop.
// DBUF=0 (DOUT=256): R5 2-barrier loop (keeps 3 blocks/CU).
// ---------------------------------------------------------------------------
template<int DOUT, int BM, int WM, int WN, int MODE, bool AFP32, int MINW, bool DBUF>
__global__ __launch_bounds__(256, MINW)
void mfma_gemm(const void* __restrict__ Xv,
               const unsigned short* __restrict__ W,
               const float* __restrict__ bias,
               const unsigned short* __restrict__ YT,  // (DOUT, 1024) bf16
               float* __restrict__ outf,
               unsigned short* __restrict__ outb,
               int din)
{
    constexpr int BN = WN * 64;
    static_assert(BN == DOUT, "block must own full output rows");
    constexpr int FM = BM / (WM * 16);
    __shared__ unsigned short Abuf[BM * 64 * (DBUF ? 2 : 1)];
    __shared__ unsigned short Bbuf[BN * 64 * (DBUF ? 2 : 1)];
    __shared__ float ssred[WN * BM];
    unsigned short* Ab0 = Abuf;
    unsigned short* Ab1 = Abuf + BM * 64;
    unsigned short* Bb0 = Bbuf;
    unsigned short* Bb1 = Bbuf + BN * 64;

    const int t = threadIdx.x, wvid = t >> 6, lane = t & 63;
    const int wr_ = wvid / WN, wc = wvid % WN;
    const int i0 = blockIdx.x * BM;
    const int nt = din >> 6;
    const bool hasagg = (i0 < KROWS);

    // ---- agg via scan-GEMM: agg = (L @ Y)/cnt from Y^T bf16 ----
    f32x4 agg[FM][4];
#pragma unroll
    for (int fi = 0; fi < FM; ++fi)
#pragma unroll
        for (int fj = 0; fj < 4; ++fj) agg[fi][fj] = (f32x4){0.f, 0.f, 0.f, 0.f};

    if (hasagg) {
        const int nt2 = (i0 + BM + 63) >> 6;    // rows only need j < i
        RegsBF<BN> sb;
        sb.load(YT, KROWS, 0, 0, t);
        for (int kt = 0; kt < nt2; ++kt) {
            if (kt) __syncthreads();
            sb.store(Bb0, t);
            __syncthreads();
            if (kt + 1 < nt2) sb.load(YT, KROWS, 0, (kt + 1) * 64, t);
#pragma unroll
            for (int kk = 0; kk < 2; ++kk) {
                const int jb = kt * 64 + kk * 32 + ((lane >> 4) << 3);
                short8 a[FM], b[4];
#pragma unroll
                for (int fi = 0; fi < FM; ++fi) {
                    const int irow = i0 + wr_ * (BM / WM) + fi * 16 + (lane & 15);
#pragma unroll
                    for (int e = 0; e < 8; ++e)
                        a[fi][e] = (short)((jb + e < irow) ? 0x3F80 : 0);
                }
#pragma unroll
                for (int fj = 0; fj < 4; ++fj) {
                    int rB = wc * 64 + fj * 16 + (lane & 15);
                    int off = (rB * 128 + kk * 64 + (lane >> 4) * 16) ^ ((rB & 7) << 4);
                    b[fj] = *reinterpret_cast<const short8*>((const char*)Bb0 + off);
                }
#pragma unroll
                for (int fi = 0; fi < FM; ++fi)
#pragma unroll
                    for (int fj = 0; fj < 4; ++fj)
                        agg[fi][fj] = __builtin_amdgcn_mfma_f32_16x16x32_bf16(
                            a[fi], b[fj], agg[fi][fj], 0, 0, 0);
            }
        }
#pragma unroll
        for (int fi = 0; fi < FM; ++fi)
#pragma unroll
            for (int reg = 0; reg < 4; ++reg) {
                int i_abs = i0 + wr_ * (BM / WM) + fi * 16 + ((lane >> 4) << 2) + reg;
                float inv = 1.0f / (float)(i_abs > 1 ? i_abs : 1);
#pragma unroll
                for (int fj = 0; fj < 4; ++fj) agg[fi][fj][reg] *= inv;
            }
        __syncthreads();                        // Bb0 reads done before reuse
    }

    // ---- bulk GEMM ----
    f32x4 acc[FM][4];
#pragma unroll
    for (int fi = 0; fi < FM; ++fi)
#pragma unroll
        for (int fj = 0; fj < 4; ++fj) acc[fi][fj] = (f32x4){0.f, 0.f, 0.f, 0.f};

    RegsBF<BN> brg;
    RegsF32<BM> arf;
    RegsBF<BM> arb;

    if (DBUF) {
        // one barrier per k-step; tile kt+1 in regs, loads for kt+2 in flight
        if (AFP32) arf.load((const float*)Xv, din, i0, 0, t);
        else       arb.load((const unsigned short*)Xv, din, i0, 0, t);
        brg.load(W, din, 0, 0, t);
        if (AFP32) arf.store(Ab0, t); else arb.store(Ab0, t);
        brg.store(Bb0, t);
        if (nt > 1) {
            if (AFP32) arf.load((const float*)Xv, din, i0, 64, t);
            else       arb.load((const unsigned short*)Xv, din, i0, 64, t);
            brg.load(W, din, 0, 64, t);
        }
        __syncthreads();
        for (int kt = 0; kt < nt; ++kt) {
            const unsigned short* Ac = (kt & 1) ? Ab1 : Ab0;
            const unsigned short* Bc = (kt & 1) ? Bb1 : Bb0;
            mfma_tile<BM, WM, WN, FM>(Ac, Bc, acc, wr_, wc, lane);
            if (kt + 1 < nt) {
                unsigned short* An = (kt & 1) ? Ab0 : Ab1;
                unsigned short* Bn = (kt & 1) ? Bb0 : Bb1;
                if (AFP32) arf.store(An, t); else arb.store(An, t);
                brg.store(Bn, t);
                if (kt + 2 < nt) {
                    const int kn = (kt + 2) * 64;
                    if (AFP32) arf.load((const float*)Xv, din, i0, kn, t);
                    else       arb.load((const unsigned short*)Xv, din, i0, kn, t);
                    brg.load(W, din, 0, kn, t);
                }
            }
            __syncthreads();
        }
    } else {
        if (AFP32) arf.load((const float*)Xv, din, i0, 0, t);
        else       arb.load((const unsigned short*)Xv, din, i0, 0, t);
        brg.load(W, din, 0, 0, t);
        for (int kt = 0; kt < nt; ++kt) {
            if (kt) __syncthreads();
            if (AFP32) arf.store(Ab0, t); else arb.store(Ab0, t);
            brg.store(Bb0, t);
            __syncthreads();
            if (kt + 1 < nt) {
                int kn = (kt + 1) * 64;
                if (AFP32) arf.load((const float*)Xv, din, i0, kn, t);
                else       arb.load((const unsigned short*)Xv, din, i0, kn, t);
                brg.load(W, din, 0, kn, t);
            }
            mfma_tile<BM, WM, WN, FM>(Ab0, Bb0, acc, wr_, wc, lane);
        }
    }

    float bb[4];
#pragma unroll
    for (int fj = 0; fj < 4; ++fj) bb[fj] = bias[wc * 64 + fj * 16 + (lane & 15)];

#pragma unroll
    for (int fi = 0; fi < FM; ++fi)
#pragma unroll
        for (int fj = 0; fj < 4; ++fj)
#pragma unroll
            for (int reg = 0; reg < 4; ++reg)
                acc[fi][fj][reg] += bb[fj] + agg[fi][fj][reg];

    float sstot[FM][4];
#pragma unroll
    for (int fi = 0; fi < FM; ++fi)
#pragma unroll
        for (int reg = 0; reg < 4; ++reg) {
            float s = 0.f;
#pragma unroll
            for (int fj = 0; fj < 4; ++fj) {
                float v = acc[fi][fj][reg];
                s += v * v;
            }
#pragma unroll
            for (int m = 8; m >= 1; m >>= 1) s += __shfl_xor(s, m);
            if ((lane & 15) == 0) {
                int rl = wr_ * (BM / WM) + fi * 16 + ((lane >> 4) << 2) + reg;
                ssred[wc * BM + rl] = s;
            }
        }
    __syncthreads();
#pragma unroll
    for (int fi = 0; fi < FM; ++fi)
#pragma unroll
        for (int reg = 0; reg < 4; ++reg) {
            int rl = wr_ * (BM / WM) + fi * 16 + ((lane >> 4) << 2) + reg;
            float s = 0.f;
#pragma unroll
            for (int c = 0; c < WN; ++c) s += ssred[c * BM + rl];
            sstot[fi][reg] = 1.0f / fmaxf(sqrtf(s), 1e-12f);
        }

#pragma unroll
    for (int fi = 0; fi < FM; ++fi)
#pragma unroll
        for (int fj = 0; fj < 4; ++fj)
#pragma unroll
            for (int reg = 0; reg < 4; ++reg) {
                int rl = wr_ * (BM / WM) + fi * 16 + ((lane >> 4) << 2) + reg;
                int cl = wc * 64 + fj * 16 + (lane & 15);
                float v = acc[fi][fj][reg] * sstot[fi][reg];
                if (MODE == 2) {
                    v = fmaxf(v, 0.f);
                    outf[(size_t)(i0 + rl) * DOUT + cl] = v;
                } else {
                    outb[(size_t)(i0 + rl) * DOUT + cl] = f2bf(v);
                }
            }
}

extern "C" void kernel_launch(void* const* d_in, const int* in_sizes, int n_in,
                              void* d_out, int out_size, void* d_ws, size_t ws_size,
                              hipStream_t stream)
{
    const float* flow = (const float*)d_in[0];
    const float* wl1 = (const float*)d_in[1];
    const float* bl1 = (const float*)d_in[2];
    const float* wr1 = (const float*)d_in[3];
    const float* wl2 = (const float*)d_in[4];
    const float* bl2 = (const float*)d_in[5];
    const float* wr2 = (const float*)d_in[6];
    const float* wl3 = (const float*)d_in[7];
    const float* bl3 = (const float*)d_in[8];
    const float* wr3 = (const float*)d_in[9];
    const float* wl4 = (const float*)d_in[10];
    const float* bl4 = (const float*)d_in[11];
    const float* wr4 = (const float*)d_in[12];
    float* out = (float*)d_out;

    char* p = (char*)d_ws;
    unsigned short* wbf = (unsigned short*)p;  p += 1 << 20;   // 327680 bf16 used
    unsigned short* xA  = (unsigned short*)p;  p += (size_t)NROWS * 128 * 2;
    unsigned short* xB  = (unsigned short*)p;  p += (size_t)NROWS * 256 * 2;
    unsigned short* YT1 = (unsigned short*)p;  p += (size_t)128 * KROWS * 2;
    unsigned short* YT2 = (unsigned short*)p;  p += (size_t)256 * KROWS * 2;
    unsigned short* YT3 = (unsigned short*)p;  p += (size_t)128 * KROWS * 2;
    unsigned short* YT4 = (unsigned short*)p;

    const unsigned short* wr1b = wbf;
    const unsigned short* wl2b = wbf + 131072;
    const unsigned short* wr2b = wbf + 163840;
    const unsigned short* wl3b = wbf + 196608;
    const unsigned short* wr3b = wbf + 229376;
    const unsigned short* wl4b = wbf + 262144;
    const unsigned short* wr4b = wbf + 294912;

    // D1: cvt + proj1 (+ tuple scalar)
    prep_kernel<<<352, 256, 0, stream>>>(flow, wl1, wr1, wl2, wr2, wl3, wr3,
                                         wl4, wr4, wbf, YT1,
                                         out + (size_t)NROWS * 256);
    // D2: main L1 (din=1024, fp32 A) — DBUF pipeline
    mfma_gemm<128, 32, 2, 2, 1, true , 4, true ><<<1024, 256, 0, stream>>>(
        flow, wr1b, bl1, YT1, nullptr, xA, 1024);
    // D3-4: L2
    proj_kernel<128, 256><<<32, 256, 0, stream>>>(xA, wl2b, YT2);
    mfma_gemm<256, 32, 1, 4, 1, false, 3, false><<<1024, 256, 0, stream>>>(
        xA, wr2b, bl2, YT2, nullptr, xB, 128);
    // D5-6: L3 — DBUF pipeline
    proj_kernel<256, 128><<<32, 256, 0, stream>>>(xB, wl3b, YT3);
    mfma_gemm<128, 32, 2, 2, 1, false, 4, true ><<<1024, 256, 0, stream>>>(
        xB, wr3b, bl3, YT3, nullptr, xA, 256);
    // D7-8: L4 + relu -> fp32 out
    proj_kernel<128, 256><<<32, 256, 0, stream>>>(xA, wl4b, YT4);
    mfma_gemm<256, 32, 1, 4, 2, false, 3, false><<<1024, 256, 0, stream>>>(
        xA, wr4b, bl4, YT4, out, nullptr, 128);
}